// Round 11
// baseline (489.333 us; speedup 1.0000x reference)
//
#include <hip/hip_runtime.h>
#include <math.h>

namespace {

constexpr int       kNME    = 262144;
constexpr int       kNDOF   = 524288;
constexpr long long kNNZ    = 16777216;   // kNME * 64
constexpr int       kNB     = 64;         // buckets
constexpr int       kBShift = 13;         // 8192 dofs / bucket
constexpr int       kBSpan  = 8192;
constexpr int       kEnt    = 2048;       // entries per producer block
constexpr int       kPerTh  = 8;          // kEnt / 256
constexpr int       kCtrStride = 16;      // counters padded to 64 B

constexpr float kEmin    = 1e-9f;
constexpr float kEmax    = 1.0f;
constexpr float kVolfrac = 0.4f;

using u32   = unsigned;
using i32x4 = __attribute__((ext_vector_type(4))) int;
using f32x4 = __attribute__((ext_vector_type(4))) float;
using u32x4 = __attribute__((ext_vector_type(4))) unsigned;

// pair = (localrow:13 bits << 19) | (fp32 bits >> 13)  [sign+exp+10 mantissa]
__device__ __forceinline__ u32 pack32(unsigned localrow, float v) {
    return (localrow << 19) | (__float_as_uint(v) >> 13);
}

// ---------------------------------------------------------------------------
// Kernel 1: per-element SIMP scale + rho partial sum.  (round-8 exact)
// ---------------------------------------------------------------------------
__global__ void scale_kernel(const float* __restrict__ W_x,
                             float* __restrict__ scale,
                             float* __restrict__ rho_sum) {
    int i = blockIdx.x * blockDim.x + threadIdx.x;
    float rho = 0.0f;
    if (i < kNME) {
        float x = W_x[i];
        rho = 1.0f / (1.0f + __expf(-x));
        scale[i] = kEmin + rho * rho * rho * (kEmax - kEmin);
    }
    for (int off = 32; off > 0; off >>= 1) rho += __shfl_down(rho, off, 64);
    __shared__ float partial[4];
    const int lane = threadIdx.x & 63;
    const int wid  = threadIdx.x >> 6;
    if (lane == 0) partial[wid] = rho;
    __syncthreads();
    if (threadIdx.x == 0)
        atomicAdd(rho_sum, partial[0] + partial[1] + partial[2] + partial[3]);
}

// ---------------------------------------------------------------------------
// Producer (round-8 exact, measured 136 us): vectorized staging loads; hist
// atomicAdd doubles as rank; 4B packed pairs; per-bucket run copy-out.
// rv[j]: bits[0:18] = row (19b), bits[19:30] = rank (12b).
// ---------------------------------------------------------------------------
__global__ __launch_bounds__(256, 8)
void producer_kernel(const float* __restrict__ K_sep,
                     const int*   __restrict__ rows,
                     const int*   __restrict__ cols,
                     const float* __restrict__ u,
                     const float* __restrict__ scale,
                     u32*         __restrict__ pairs,
                     unsigned*    __restrict__ counters,  // [kNB*R*kCtrStride]
                     long long chunk_base, unsigned capSub, int R) {
    __shared__ unsigned hist[kNB], ofs[kNB], gbase[kNB];
    __shared__ u32      sorted[kEnt];     // 8 KB

    const int tid = threadIdx.x;
    const int sub = blockIdx.x & (R - 1);
    if (tid < kNB) hist[tid] = 0u;
    __syncthreads();

    const long long i0 =
        chunk_base + (long long)blockIdx.x * kEnt + (long long)tid * kPerTh;
    i32x4 r0 = __builtin_nontemporal_load((const i32x4*)(rows + i0));
    i32x4 r1 = __builtin_nontemporal_load((const i32x4*)(rows + i0) + 1);
    i32x4 c0 = __builtin_nontemporal_load((const i32x4*)(cols + i0));
    i32x4 c1 = __builtin_nontemporal_load((const i32x4*)(cols + i0) + 1);
    f32x4 k0 = __builtin_nontemporal_load((const f32x4*)(K_sep + i0));
    f32x4 k1 = __builtin_nontemporal_load((const f32x4*)(K_sep + i0) + 1);
    const float s = scale[(int)(i0 >> 6)];   // all 8 share one element

    unsigned rv[kPerTh];
    float    vv[kPerTh];
#pragma unroll
    for (int j = 0; j < 4; ++j) {
        rv[j]     = (unsigned)r0[j];  vv[j]     = k0[j] * s * u[c0[j]];
        rv[j + 4] = (unsigned)r1[j];  vv[j + 4] = k1[j] * s * u[c1[j]];
    }
    // Histogram; the returned old value IS this entry's rank in its bucket.
#pragma unroll
    for (int j = 0; j < kPerTh; ++j)
        rv[j] |= atomicAdd(&hist[rv[j] >> kBShift], 1u) << 19;
    __syncthreads();

    // Wave 0: exclusive scan over 64 buckets + reserve global sub-ranges.
    if (tid < kNB) {
        unsigned h = hist[tid];
        unsigned x = h;
#pragma unroll
        for (int off = 1; off < kNB; off <<= 1) {
            unsigned y = __shfl_up(x, off, 64);
            if (tid >= off) x += y;
        }
        ofs[tid]   = x - h;
        gbase[tid] = atomicAdd(&counters[(tid * R + sub) * kCtrStride], h);
    }
    __syncthreads();

    // Scatter into sorted LDS order — no atomics (rank precomputed).
#pragma unroll
    for (int j = 0; j < kPerTh; ++j) {
        unsigned row = rv[j] & 0x7FFFFu;
        unsigned b   = row >> kBShift;
        unsigned pos = ofs[b] + (rv[j] >> 19);
        sorted[pos]  = pack32(row & (kBSpan - 1), vv[j]);
    }
    __syncthreads();

    // Coalesced copy-out: one wave per bucket run.
    const int wid = tid >> 6, lane = tid & 63;
    for (int b = wid; b < kNB; b += 4) {
        const unsigned s0 = ofs[b];
        const unsigned n  = hist[b];
        const unsigned g  = gbase[b];
        u32* dst = pairs + (size_t)(b * R + sub) * capSub + g;
        for (unsigned i = lane; i < n; i += 64) {
            if (g + i < capSub)
                __builtin_nontemporal_store(sorted[s0 + i], &dst[i]);
        }
    }
}

// ---------------------------------------------------------------------------
// Consumer+norm fused (NC==1 path): ONE block per bucket (1024 threads).
// Accumulates all R sub-regions into a single 32 KB LDS tile, then computes
// sum((tile - f)^2) for its 8192 dofs directly; done-counter finalize.
// acc layout: acc[0]=rho_sum, acc[1]=norm_sum, acc[2]=done counter (uint).
// ---------------------------------------------------------------------------
__global__ __launch_bounds__(1024, 4)
void consumer_norm_kernel(const u32*      __restrict__ pairs,
                          const unsigned* __restrict__ counters,
                          const float*    __restrict__ f,
                          float*          __restrict__ acc_g,
                          float*          __restrict__ out,
                          unsigned capSub, int R) {
    const int b = blockIdx.x;
    __shared__ float tile[kBSpan];       // 32 KB
    __shared__ float wpart[16];
    for (int i = threadIdx.x; i < kBSpan / 4; i += 1024)
        ((f32x4*)tile)[i] = f32x4{0.0f, 0.0f, 0.0f, 0.0f};
    __syncthreads();

    for (int sub = 0; sub < R; ++sub) {
        unsigned cnt = counters[(b * R + sub) * kCtrStride];
        if (cnt > capSub) cnt = capSub;
        const u32* p = pairs + (size_t)(b * R + sub) * capSub;
        const unsigned aligned = cnt & ~3u;
        for (unsigned i = 4 * threadIdx.x; i < aligned; i += 4096) {
            u32x4 e = __builtin_nontemporal_load((const u32x4*)(p + i));
#pragma unroll
            for (int j = 0; j < 4; ++j)
                atomicAdd(&tile[e[j] >> 19], __uint_as_float(e[j] << 13));
        }
        if (threadIdx.x < (cnt - aligned)) {
            u32 e = p[aligned + threadIdx.x];
            atomicAdd(&tile[e >> 19], __uint_as_float(e << 13));
        }
    }
    __syncthreads();

    // Norm for this bucket's dofs (2 vec-iterations per thread).
    float a = 0.0f;
    for (int k = 4 * threadIdx.x; k < kBSpan; k += 4096) {
        f32x4 t  = *(const f32x4*)&tile[k];
        f32x4 fv = *(const f32x4*)(f + (size_t)b * kBSpan + k);
        f32x4 d  = t - fv;
        a += d[0] * d[0] + d[1] * d[1] + d[2] * d[2] + d[3] * d[3];
    }
    for (int off = 32; off > 0; off >>= 1) a += __shfl_down(a, off, 64);
    const int lane = threadIdx.x & 63, wid = threadIdx.x >> 6;
    if (lane == 0) wpart[wid] = a;
    __syncthreads();
    if (threadIdx.x == 0) {
        float t = 0.0f;
#pragma unroll
        for (int w = 0; w < 16; ++w) t += wpart[w];
        atomicAdd(&acc_g[1], t);
        __threadfence();
        unsigned done = atomicAdd((unsigned*)&acc_g[2], 1u);
        if (done == gridDim.x - 1) {
            float rs = __hip_atomic_load(&acc_g[0], __ATOMIC_RELAXED,
                                         __HIP_MEMORY_SCOPE_AGENT);
            float ns = __hip_atomic_load(&acc_g[1], __ATOMIC_RELAXED,
                                         __HIP_MEMORY_SCOPE_AGENT);
            float rho_mean = rs * (1.0f / (float)kNME);
            out[0] = fmaxf(rho_mean - kVolfrac, 0.0f) + sqrtf(ns);
        }
    }
}

// ---------------------------------------------------------------------------
// NC>1 path: consumer into partial planes + fused norm/finalize (round 10).
// ---------------------------------------------------------------------------
__global__ __launch_bounds__(512, 8)
void consumer_kernel(const u32*      __restrict__ pairs,
                     const unsigned* __restrict__ counters,
                     float*          __restrict__ partial,
                     unsigned capSub, int R, int accum) {
    const int b   = blockIdx.x / R;
    const int sub = blockIdx.x - b * R;
    unsigned cnt = counters[(b * R + sub) * kCtrStride];
    if (cnt > capSub) cnt = capSub;

    __shared__ float acc[kBSpan];
    for (int i = threadIdx.x; i < kBSpan; i += 512) acc[i] = 0.0f;
    __syncthreads();

    const u32* p = pairs + (size_t)(b * R + sub) * capSub;
    const unsigned aligned = cnt & ~3u;
    for (unsigned i = 4 * threadIdx.x; i < aligned; i += 2048) {
        u32x4 e = __builtin_nontemporal_load((const u32x4*)(p + i));
#pragma unroll
        for (int j = 0; j < 4; ++j)
            atomicAdd(&acc[e[j] >> 19], __uint_as_float(e[j] << 13));
    }
    if (threadIdx.x < (cnt - aligned)) {
        u32 e = p[aligned + threadIdx.x];
        atomicAdd(&acc[e >> 19], __uint_as_float(e << 13));
    }
    __syncthreads();

    float* dst = partial + (size_t)(b * R + sub) * kBSpan;
    if (accum) {
        for (int k = threadIdx.x; k < kBSpan; k += 512) dst[k] += acc[k];
    } else {
        for (int k = threadIdx.x; k < kBSpan; k += 512) dst[k] = acc[k];
    }
}

__global__ void norm_kernel(const float* __restrict__ partial,
                            const float* __restrict__ f,
                            float* __restrict__ acc,
                            float* __restrict__ out, int R) {
    const int b  = blockIdx.x >> 3;
    const int i0 = (blockIdx.x & 7) * 1024 + threadIdx.x * 4;
    f32x4 s = {0.0f, 0.0f, 0.0f, 0.0f};
    for (int r = 0; r < R; ++r)
        s += *(const f32x4*)(partial + (size_t)(b * R + r) * kBSpan + i0);
    f32x4 fv = *(const f32x4*)(f + (size_t)b * kBSpan + i0);
    f32x4 d  = s - fv;
    float a = d[0] * d[0] + d[1] * d[1] + d[2] * d[2] + d[3] * d[3];
    for (int off = 32; off > 0; off >>= 1) a += __shfl_down(a, off, 64);
    __shared__ float partial_s[4];
    const int lane = threadIdx.x & 63;
    const int wid  = threadIdx.x >> 6;
    if (lane == 0) partial_s[wid] = a;
    __syncthreads();
    if (threadIdx.x == 0) {
        atomicAdd(&acc[1],
                  partial_s[0] + partial_s[1] + partial_s[2] + partial_s[3]);
        __threadfence();
        unsigned done = atomicAdd((unsigned*)&acc[2], 1u);
        if (done == gridDim.x - 1) {
            float rs = __hip_atomic_load(&acc[0], __ATOMIC_RELAXED,
                                         __HIP_MEMORY_SCOPE_AGENT);
            float ns = __hip_atomic_load(&acc[1], __ATOMIC_RELAXED,
                                         __HIP_MEMORY_SCOPE_AGENT);
            float rho_mean = rs * (1.0f / (float)kNME);
            out[0] = fmaxf(rho_mean - kVolfrac, 0.0f) + sqrtf(ns);
        }
    }
}

// ---------------------------------------------------------------------------
// Fallback path (device atomics) if workspace is too small.
// ---------------------------------------------------------------------------
__global__ void scatter_dev_kernel(const float* __restrict__ K_sep,
                                   const int*   __restrict__ rows,
                                   const int*   __restrict__ cols,
                                   const float* __restrict__ u,
                                   const float* __restrict__ scale,
                                   float* __restrict__ Ku) {
    long long i = (long long)blockIdx.x * blockDim.x + threadIdx.x;
    if (i >= kNNZ) return;
    float s = scale[(int)(i >> 6)];
    atomicAdd(&Ku[rows[i]], K_sep[i] * s * u[cols[i]]);
}

__global__ void norm1_kernel(const float* __restrict__ Ku,
                             const float* __restrict__ f,
                             float* __restrict__ norm_sum) {
    float a = 0.0f;
    for (int i = blockIdx.x * blockDim.x + threadIdx.x; i < kNDOF;
         i += gridDim.x * blockDim.x) {
        float d = Ku[i] - f[i];
        a += d * d;
    }
    for (int off = 32; off > 0; off >>= 1) a += __shfl_down(a, off, 64);
    __shared__ float partial_s[4];
    const int lane = threadIdx.x & 63;
    const int wid  = threadIdx.x >> 6;
    if (lane == 0) partial_s[wid] = a;
    __syncthreads();
    if (threadIdx.x == 0)
        atomicAdd(norm_sum,
                  partial_s[0] + partial_s[1] + partial_s[2] + partial_s[3]);
}

__global__ void finalize_kernel(const float* __restrict__ acc,
                                float* __restrict__ out) {
    if (threadIdx.x == 0 && blockIdx.x == 0) {
        float rho_mean = acc[0] * (1.0f / (float)kNME);
        float vol = fmaxf(rho_mean - kVolfrac, 0.0f);
        out[0] = vol + sqrtf(acc[1]);
    }
}

}  // namespace

extern "C" void kernel_launch(void* const* d_in, const int* in_sizes, int n_in,
                              void* d_out, int out_size, void* d_ws, size_t ws_size,
                              hipStream_t stream) {
    const float* W_x   = (const float*)d_in[0];
    const float* K_sep = (const float*)d_in[1];
    const int*   idx   = (const int*)d_in[2];
    const float* u     = (const float*)d_in[3];
    const float* f     = (const float*)d_in[4];
    const int* rows = idx;
    const int* cols = idx + kNNZ;

    float* ws = (float*)d_ws;
    const size_t avail = ws_size / sizeof(float);

    // Pick (num_chunks, R, cap margin): first config that fits.
    struct Opt { int nc, R; unsigned margin; };
    const Opt opts[] = {{1, 16, 2048}, {1, 16, 1024}, {1, 8, 2048},
                        {2, 8, 2048},  {2, 8, 1024},  {4, 8, 1024},
                        {4, 4, 1024},  {8, 4, 1024}};
    int NC = -1, R = 16;
    unsigned capSub = 0;
    size_t ctrF = 0, partialF = 0;
    for (const Opt& o : opts) {
        long long perCell = kNNZ / ((long long)o.nc * kNB * o.R);
        unsigned  mc      = (unsigned)perCell + o.margin;
        size_t cf = (size_t)o.nc * kNB * o.R * kCtrStride;
        size_t pf = (o.nc > 1) ? (size_t)kNB * o.R * kBSpan : 0;  // NC=1: no partial
        size_t need = 16 + cf + pf + (size_t)kNME +
                      (size_t)kNB * o.R * (size_t)mc;             // pairs are u32
        if (need <= avail) {
            NC = o.nc; R = o.R; capSub = mc; ctrF = cf; partialF = pf;
            break;
        }
    }

    if (NC < 0) {
        // Fallback: device-atomic scatter (fits in ~3.2 MB).
        float* Ku    = ws;
        float* scale = ws + kNDOF;
        float* acc   = ws + kNDOF + kNME;
        hipMemsetAsync(ws, 0, (size_t)(kNDOF + kNME + 16) * sizeof(float), stream);
        scale_kernel<<<kNME / 256, 256, 0, stream>>>(W_x, scale, acc);
        scatter_dev_kernel<<<(int)(kNNZ / 256), 256, 0, stream>>>(
            K_sep, rows, cols, u, scale, Ku);
        norm1_kernel<<<2048, 256, 0, stream>>>(Ku, f, acc + 1);
        finalize_kernel<<<1, 64, 0, stream>>>(acc, (float*)d_out);
        return;
    }

    float*    acc      = ws;                          // [16] (rho, norm, done)
    unsigned* counters = (unsigned*)(ws + 16);        // [NC][kNB*R*kCtrStride]
    float*    partial  = ws + 16 + ctrF;              // [kNB*R*kBSpan] (NC>1)
    float*    scale    = partial + partialF;          // [kNME]
    u32*      pairs    = (u32*)(scale + kNME);        // [kNB*R*capSub]

    // Zero acc + counters (replay-safe).
    hipMemsetAsync(ws, 0, (16 + ctrF) * sizeof(float), stream);

    scale_kernel<<<kNME / 256, 256, 0, stream>>>(W_x, scale, acc);

    const long long chunk = kNNZ / NC;
    const int prod_blocks = (int)(chunk / kEnt);
    if (NC == 1) {
        producer_kernel<<<prod_blocks, 256, 0, stream>>>(
            K_sep, rows, cols, u, scale, pairs, counters, 0LL, capSub, R);
        consumer_norm_kernel<<<kNB, 1024, 0, stream>>>(
            pairs, counters, f, acc, (float*)d_out, capSub, R);
    } else {
        for (int c = 0; c < NC; ++c) {
            unsigned* ctr = counters + (size_t)c * kNB * R * kCtrStride;
            producer_kernel<<<prod_blocks, 256, 0, stream>>>(
                K_sep, rows, cols, u, scale, pairs, ctr, chunk * c, capSub, R);
            consumer_kernel<<<kNB * R, 512, 0, stream>>>(
                pairs, ctr, partial, capSub, R, /*accum=*/c > 0 ? 1 : 0);
        }
        norm_kernel<<<kNB * (kBSpan / 1024), 256, 0, stream>>>(
            partial, f, acc, (float*)d_out, R);
    }
}